// Round 18
// baseline (90.513 us; speedup 1.0000x reference)
//
#include <hip/hip_runtime.h>
#include <cstdint>
#include <cstddef>

// MemristorDense: y[b,o] = C * sum_i [ gp*exp2(Ep*L) - gn*exp2(En*L) ]
// L[b,i]=log2(2x), E=log2(n) (precomputed table), g=kG*|w|+G_MIN (fma, no log2),
// C=0.5*maxw/(G_MAX-G_MIN). x=0 -> L=-inf -> exp2=0 (correct).
// R18: hot loop stripped to exp2-only trans. (1) Elog table from k_prep kills
// Ep/En log2s; (2) g-fold (acc=fma(g,exp2,acc)) kills Wp/Wn log2s; (3) LT tile
// staged to LDS once per block kills the 4 per-step broadcast loads. Per step:
// 3 coalesced VMEM + 4 broadcast ds_read_b128 + 32 exp2 + ~70 VALU.

#define B128 128
#define NIN  1024
#define NI   1025
#define NO   512
#define NJ   1024
#define GMIN 1.0e-5f
#define GSPAN (1.0e-3f - 1.0e-5f)
#define ZCH  8      // K-chunks over [0,1024)
#define CHUNK 128

__device__ __forceinline__ float flog2(float x) { return __builtin_amdgcn_logf(x); }
__device__ __forceinline__ float fexp2(float x) { return __builtin_amdgcn_exp2f(x); }

// Kernel 1 (grid 256 x 1024): zero out, LT[i][b]=1+log2(x[b][i]),
// Elog[i][j]=log2(nd[i][j]), per-block |w| max -> bmax[256].
__global__ __launch_bounds__(1024) void k_prep(
    const float* __restrict__ x, const float* __restrict__ nd,
    const float* __restrict__ wp, const float* __restrict__ wn,
    const float* __restrict__ bp, const float* __restrict__ bn,
    float* __restrict__ LT, float* __restrict__ Elog,
    float* __restrict__ bmax, float* __restrict__ out)
{
    const int tid = blockIdx.x * 1024 + threadIdx.x;   // [0, 262144)

    if (tid < B128 * NO) out[tid] = 0.0f;

    if (tid < NI * B128) {
        int i = tid >> 7, b = tid & 127;
        float xv = (i < NIN) ? x[b * NIN + i] : 1.0f;
        LT[tid] = 1.0f + flog2(xv);                 // log2(2x); x=0 -> -inf (correct)
    }

    for (int t = tid; t < NI * NJ; t += 262144)     // 1,049,600 elements
        Elog[t] = flog2(nd[t]);

    // NIN*NO = 524288 = 2 * 262144 exactly
    float m = fmaxf(fmaxf(__builtin_fabsf(wp[tid]), __builtin_fabsf(wn[tid])),
                    fmaxf(__builtin_fabsf(wp[tid + 262144]), __builtin_fabsf(wn[tid + 262144])));
    if (tid < NO) m = fmaxf(m, fmaxf(__builtin_fabsf(bp[tid]), __builtin_fabsf(bn[tid])));

    __shared__ float red[16];
    #pragma unroll
    for (int off = 32; off > 0; off >>= 1) m = fmaxf(m, __shfl_down(m, off, 64));
    if ((threadIdx.x & 63) == 0) red[threadIdx.x >> 6] = m;
    __syncthreads();
    if (threadIdx.x < 16) {
        m = red[threadIdx.x];
        #pragma unroll
        for (int off = 8; off > 0; off >>= 1) m = fmaxf(m, __shfl_down(m, off, 16));
        if (threadIdx.x == 0) bmax[blockIdx.x] = m;
    }
}

// Kernel 2: grid (8 o-tiles, 8 b-tiles, 8 K-chunks) x 512 threads (8 waves).
// Wave s: i = z*128 + s + 8k, k in [0,16). 16 batches/wave. L-tile (128x16,
// 8KB) staged to LDS once; hot loop: Elog float2 + wp + wn loads, 32 exp2,
// acc=fma(g,exp2(E*L),acc). LDS diff-reduce epilogue + 0.5M atomics.
__global__ __launch_bounds__(512) void k_main(
    const float* __restrict__ nd,
    const float* __restrict__ wp, const float* __restrict__ wn,
    const float* __restrict__ bp, const float* __restrict__ bn,
    const float* __restrict__ LT, const float* __restrict__ Elog,
    const float* __restrict__ bmax, float* __restrict__ out)
{
    const int lane = threadIdx.x & 63;
    const int s    = threadIdx.x >> 6;      // wave id [0,8)
    const int o    = (blockIdx.x << 6) + lane;
    const int b0   = blockIdx.y << 4;       // 16 batches per block
    const int i0   = blockIdx.z * CHUNK;    // chunk base

    __shared__ float lds[8 * 64 * 17];      // 34816 B; first 8KB doubles as L-tile
    float* tile = lds;                      // tile[ii][16], ii in [0,128)

    // stage the block's L-tile: 512 threads x one float4 = 8KB
    {
        const int t = threadIdx.x;
        const int row = t >> 2, c4 = (t & 3) << 2;
        const float4 v = *(const float4*)(LT + (size_t)(i0 + row) * B128 + b0 + c4);
        *(float4*)(tile + row * 16 + c4) = v;
    }

    // reduce 256 per-block maxima (redundant per wave; L2-hot)
    float m = fmaxf(fmaxf(bmax[lane], bmax[lane + 64]),
                    fmaxf(bmax[lane + 128], bmax[lane + 192]));
    #pragma unroll
    for (int off = 32; off > 0; off >>= 1) m = fmaxf(m, __shfl_down(m, off, 64));
    const float maxw = __shfl(m, 0, 64);
    const float kG = GSPAN / maxw;
    const float C  = 0.5f * maxw / GSPAN;

    __syncthreads();   // tile ready

    const float* pEl = Elog + (size_t)(i0 + s) * NJ + 2 * o;
    const float* pwp = wp + (size_t)(i0 + s) * NO + o;
    const float* pwn = wn + (size_t)(i0 + s) * NO + o;

    float accp[16], accn[16];
    #pragma unroll
    for (int k = 0; k < 16; ++k) { accp[k] = 0.0f; accn[k] = 0.0f; }

    // prologue loads for k=0
    float2 el = *(const float2*)pEl;
    float wvp = *pwp;
    float wvn = *pwn;

    #pragma unroll 2
    for (int k = 0; k < 15; ++k) {
        pEl += 8 * NJ; pwp += 8 * NO; pwn += 8 * NO;
        const float2 el_n = *(const float2*)pEl;
        const float wp_n = *pwp;
        const float wn_n = *pwn;

        const float gp = __builtin_fmaf(kG, __builtin_fabsf(wvp), GMIN);
        const float gn = __builtin_fmaf(kG, __builtin_fabsf(wvn), GMIN);

        const float* trow = tile + (s + 8 * k) * 16;
        const float4 La = *(const float4*)(trow);
        const float4 Lb = *(const float4*)(trow + 4);
        const float4 Lc = *(const float4*)(trow + 8);
        const float4 Ld = *(const float4*)(trow + 12);
        const float Lv[16] = {La.x, La.y, La.z, La.w, Lb.x, Lb.y, Lb.z, Lb.w,
                              Lc.x, Lc.y, Lc.z, Lc.w, Ld.x, Ld.y, Ld.z, Ld.w};
        #pragma unroll
        for (int j = 0; j < 16; ++j) {
            accp[j] = __builtin_fmaf(gp, fexp2(el.x * Lv[j]), accp[j]);
            accn[j] = __builtin_fmaf(gn, fexp2(el.y * Lv[j]), accn[j]);
        }

        el = el_n; wvp = wp_n; wvn = wn_n;
    }

    // last step (k=15), no prefetch
    {
        const float gp = __builtin_fmaf(kG, __builtin_fabsf(wvp), GMIN);
        const float gn = __builtin_fmaf(kG, __builtin_fabsf(wvn), GMIN);
        const float* trow = tile + (s + 8 * 15) * 16;
        const float4 La = *(const float4*)(trow);
        const float4 Lb = *(const float4*)(trow + 4);
        const float4 Lc = *(const float4*)(trow + 8);
        const float4 Ld = *(const float4*)(trow + 12);
        const float Lv[16] = {La.x, La.y, La.z, La.w, Lb.x, Lb.y, Lb.z, Lb.w,
                              Lc.x, Lc.y, Lc.z, Lc.w, Ld.x, Ld.y, Ld.z, Ld.w};
        #pragma unroll
        for (int j = 0; j < 16; ++j) {
            accp[j] = __builtin_fmaf(gp, fexp2(el.x * Lv[j]), accp[j]);
            accn[j] = __builtin_fmaf(gn, fexp2(el.y * Lv[j]), accn[j]);
        }
    }

    __syncthreads();   // all tile reads done; safe to overwrite with partials

    // LDS diff-reduce across the 8 waves. Row stride 17 floats -> conflict-free.
    {
        const int base = (s * 64 + lane) * 17;
        #pragma unroll
        for (int j = 0; j < 16; ++j) lds[base + j] = accp[j] - accn[j];
    }
    __syncthreads();

    // 512 threads -> 1024 outputs: 2 per thread.
    {
        const int l = threadIdx.x & 63;
        #pragma unroll
        for (int r = 0; r < 2; ++r) {
            const int b = (threadIdx.x >> 6) + (r << 3);   // [0,16)
            float sum = 0.0f;
            #pragma unroll
            for (int w = 0; w < 8; ++w) sum += lds[(w * 64 + l) * 17 + b];

            // bias row (i=1024): L=1 -> term = n*g (pure mul), once per (b,o),
            // added by the z==0 block. Each (b,l) pair unique within block.
            if (blockIdx.z == 0) {
                const int oo = (blockIdx.x << 6) + l;
                const float2 nb = *(const float2*)(nd + (size_t)NIN * NJ + 2 * oo);
                const float gp = __builtin_fmaf(kG, __builtin_fabsf(bp[oo]), GMIN);
                const float gn = __builtin_fmaf(kG, __builtin_fabsf(bn[oo]), GMIN);
                sum += nb.x * gp - nb.y * gn;
            }
            unsafeAtomicAdd(out + (size_t)(b0 + b) * NO + (blockIdx.x << 6) + l, C * sum);
        }
    }
}

extern "C" void kernel_launch(void* const* d_in, const int* in_sizes, int n_in,
                              void* d_out, int out_size, void* d_ws, size_t ws_size,
                              hipStream_t stream)
{
    const float* x  = (const float*)d_in[0];
    const float* wp = (const float*)d_in[1];
    const float* wn = (const float*)d_in[2];
    const float* bp = (const float*)d_in[3];
    const float* bn = (const float*)d_in[4];
    const float* nd = (const float*)d_in[5];
    float* out = (float*)d_out;

    unsigned char* ws = (unsigned char*)d_ws;
    float* bmax = (float*)ws;                       // 256 floats
    float* LT   = (float*)(ws + 4096);              // 1025*128*4 = 524800 B
    float* Elog = (float*)(ws + 4096 + 525056);     // 1025*1024*4 = 4198400 B

    k_prep<<<256, 1024, 0, stream>>>(x, nd, wp, wn, bp, bn, LT, Elog, bmax, out);
    k_main<<<dim3(8, 8, ZCH), 512, 0, stream>>>(nd, wp, wn, bp, bn, LT, Elog, bmax, out);
}